// Round 1
// baseline (440.405 us; speedup 1.0000x reference)
//
#include <hip/hip_runtime.h>

// Problem constants (from reference setup_inputs)
constexpr int BB = 16;        // batch
constexpr int HH = 512;
constexpr int WW = 512;
constexpr int HW = HH * WW;   // 262144 = 2^18
constexpr int NPIX = BB * HW; // 4,194,304

// 11-tap Gaussian, theta=1: k[d] = exp(-d^2/2)/sum. Sum of exp terms =
// 2.5066282575371262 (≈ sqrt(2*pi) within 7e-9 rel), so normalized taps are
// numerically the normal pdf values to ~1e-8 — far below validation threshold.
__device__ __constant__ float c_gk[11] = {
    1.4867195147342977e-06f,
    1.3383022576488537e-04f,
    4.4318484119380075e-03f,
    5.3990966513188063e-02f,
    2.4197072451914337e-01f,
    3.9894228040143270e-01f,
    2.4197072451914337e-01f,
    5.3990966513188063e-02f,
    4.4318484119380075e-03f,
    1.3383022576488537e-04f,
    1.4867195147342977e-06f,
};

// ---------------------------------------------------------------------------
// Kernel 1: 3x3 conv, C_in=3 -> C_out=2, zero-padded SAME. Writes both the
// persistent unary term (ws) and the initial cur (d_out).
// ---------------------------------------------------------------------------
__global__ __launch_bounds__(256) void conv3x3(
    const float* __restrict__ x, const float* __restrict__ w,
    const float* __restrict__ bias, float* __restrict__ unary,
    float* __restrict__ cur)
{
    int p = blockIdx.x * 256 + threadIdx.x;
    if (p >= NPIX) return;
    int b   = p >> 18;           // / HW
    int rem = p & (HW - 1);
    int y   = rem >> 9;          // / WW
    int xx  = rem & (WW - 1);

    const float* xb = x + (size_t)b * 3 * HW;
    float acc0 = bias[0];
    float acc1 = bias[1];
#pragma unroll
    for (int ci = 0; ci < 3; ++ci) {
        const float* xc = xb + ci * HW;
#pragma unroll
        for (int kh = 0; kh < 3; ++kh) {
            int yy = y + kh - 1;
            if (yy < 0 || yy >= HH) continue;
#pragma unroll
            for (int kw = 0; kw < 3; ++kw) {
                int xi = xx + kw - 1;
                if (xi < 0 || xi >= WW) continue;
                float v = xc[yy * WW + xi];
                acc0 = fmaf(v, w[(0 * 3 + ci) * 9 + kh * 3 + kw], acc0);
                acc1 = fmaf(v, w[(1 * 3 + ci) * 9 + kh * 3 + kw], acc1);
            }
        }
    }
    size_t o = (size_t)b * 2 * HW + rem;
    unary[o] = acc0;
    unary[o + HW] = acc1;
    cur[o] = acc0;
    cur[o + HW] = acc1;
}

// ---------------------------------------------------------------------------
// Kernel 2: fused channel-softmax + vertical 11-tap blur.
// q0 = sigmoid(c0-c1), q1 = 1-q0 computed per tap (cheap: 1 exp + 1 div for
// BOTH channels). Out-of-range rows contribute 0 (zero-padded blur of q).
// ---------------------------------------------------------------------------
__global__ __launch_bounds__(256) void sm_vblur(
    const float* __restrict__ cur, float* __restrict__ t)
{
    int p = blockIdx.x * 256 + threadIdx.x;
    if (p >= NPIX) return;
    int b   = p >> 18;
    int rem = p & (HW - 1);
    int y   = rem >> 9;
    int xx  = rem & (WW - 1);

    const float* c0 = cur + (size_t)b * 2 * HW + xx;
    const float* c1 = c0 + HW;
    float acc0 = 0.f, acc1 = 0.f;
#pragma unroll
    for (int dy = -5; dy <= 5; ++dy) {
        int yy = y + dy;
        if (yy < 0 || yy >= HH) continue;
        float a  = c0[yy * WW];
        float bb = c1[yy * WW];
        // 2-class softmax via clamped sigmoid (overflow-safe, ~1e-13 err)
        float d  = fminf(fmaxf(bb - a, -30.f), 30.f);
        float e  = __expf(d);
        float inv = 1.0f / (1.0f + e);
        float q0 = inv;          // e^{c0} / (e^{c0}+e^{c1})
        float q1 = e * inv;      // e^{c1} / (e^{c0}+e^{c1})
        float k  = c_gk[dy + 5];
        acc0 = fmaf(k, q0, acc0);
        acc1 = fmaf(k, q1, acc1);
    }
    size_t o = (size_t)b * 2 * HW + rem;
    t[o] = acc0;
    t[o + HW] = acc1;
}

// ---------------------------------------------------------------------------
// Kernel 3: horizontal 11-tap blur + unary add -> new cur.
// ---------------------------------------------------------------------------
__global__ __launch_bounds__(256) void hblur_add(
    const float* __restrict__ t, const float* __restrict__ unary,
    float* __restrict__ cur)
{
    int p = blockIdx.x * 256 + threadIdx.x;
    if (p >= NPIX) return;
    int b   = p >> 18;
    int rem = p & (HW - 1);
    int y   = rem >> 9;
    int xx  = rem & (WW - 1);

    const float* r0 = t + (size_t)b * 2 * HW + y * WW;
    const float* r1 = r0 + HW;
    float acc0 = 0.f, acc1 = 0.f;
#pragma unroll
    for (int dx = -5; dx <= 5; ++dx) {
        int xi = xx + dx;
        if (xi < 0 || xi >= WW) continue;
        float k = c_gk[dx + 5];
        acc0 = fmaf(k, r0[xi], acc0);
        acc1 = fmaf(k, r1[xi], acc1);
    }
    size_t o = (size_t)b * 2 * HW + rem;
    cur[o]      = unary[o] + acc0;
    cur[o + HW] = unary[o + HW] + acc1;
}

extern "C" void kernel_launch(void* const* d_in, const int* in_sizes, int n_in,
                              void* d_out, int out_size, void* d_ws, size_t ws_size,
                              hipStream_t stream) {
    const float* x    = (const float*)d_in[0];   // (16,3,512,512)
    const float* w    = (const float*)d_in[1];   // (2,3,3,3)
    const float* bias = (const float*)d_in[2];   // (2,)

    float* cur   = (float*)d_out;                       // (16,2,512,512)
    float* unary = (float*)d_ws;                        // 33.5 MB
    float* tmp   = unary + (size_t)BB * 2 * HW;         // 33.5 MB

    constexpr int grid = (NPIX + 255) / 256;  // 16384 blocks

    conv3x3<<<grid, 256, 0, stream>>>(x, w, bias, unary, cur);
    for (int it = 0; it < 5; ++it) {
        sm_vblur<<<grid, 256, 0, stream>>>(cur, tmp);
        hblur_add<<<grid, 256, 0, stream>>>(tmp, unary, cur);
    }
}

// Round 2
// 144.311 us; speedup vs baseline: 3.0518x; 3.0518x over previous
//
#include <hip/hip_runtime.h>

constexpr int BB = 16;        // batch
constexpr int HH = 512;
constexpr int WW = 512;
constexpr int HW = HH * WW;   // 262144 = 2^18

// 11-tap Gaussian, theta=1, normalized (== normal pdf values to ~1e-8 rel).
// constexpr so taps become inline 32-bit literals (no constant-mem loads).
__device__ constexpr float GK[11] = {
    1.4867195147342977e-06f,
    1.3383022576488537e-04f,
    4.4318484119380075e-03f,
    5.3990966513188063e-02f,
    2.4197072451914337e-01f,
    3.9894228040143270e-01f,
    2.4197072451914337e-01f,
    5.3990966513188063e-02f,
    4.4318484119380075e-03f,
    1.3383022576488537e-04f,
    1.4867195147342977e-06f,
};

// ---------------------------------------------------------------------------
// Kernel 1: 3x3 conv, C_in=3 -> C_out=2, SAME zero-pad. 4 px/thread, float4.
// Writes unary only (iter 0 reads unary as cur).
// ---------------------------------------------------------------------------
__global__ __launch_bounds__(256) void conv3x3_v4(
    const float* __restrict__ x, const float* __restrict__ w,
    const float* __restrict__ bias, float* __restrict__ unary)
{
    // XCD-chunked swizzle (grid 4096, 4096%8==0 -> bijective)
    int bid = blockIdx.x;
    int sb  = (bid & 7) * 512 + (bid >> 3);
    int t   = sb * 256 + threadIdx.x;        // 1,048,576 threads, 4 px each
    int b   = t >> 16;                       // HW/4 = 65536 quads per plane
    int rem = t & 65535;
    int y   = rem >> 7;                      // 128 quads per row
    int x0  = (rem & 127) << 2;

    float acc0[4], acc1[4];
    float b0 = bias[0], b1 = bias[1];
#pragma unroll
    for (int j = 0; j < 4; ++j) { acc0[j] = b0; acc1[j] = b1; }

    const float* xb = x + (size_t)b * 3 * HW;
#pragma unroll
    for (int ci = 0; ci < 3; ++ci) {
        const float* xc = xb + ci * HW;
#pragma unroll
        for (int kh = 0; kh < 3; ++kh) {
            int yy = y + kh - 1;
            if (yy < 0 || yy >= HH) continue;
            const float* r = xc + yy * WW;
            float4 c = *(const float4*)(r + x0);
            float l  = (x0 > 0)      ? r[x0 - 1] : 0.f;
            float rr = (x0 < WW - 4) ? r[x0 + 4] : 0.f;
            float v[6] = {l, c.x, c.y, c.z, c.w, rr};
            const float* wp0 = w + (0 * 3 + ci) * 9 + kh * 3;
            const float* wp1 = w + (1 * 3 + ci) * 9 + kh * 3;
            float w00 = wp0[0], w01 = wp0[1], w02 = wp0[2];
            float w10 = wp1[0], w11 = wp1[1], w12 = wp1[2];
#pragma unroll
            for (int j = 0; j < 4; ++j) {
                acc0[j] = fmaf(w00, v[j], fmaf(w01, v[j + 1], fmaf(w02, v[j + 2], acc0[j])));
                acc1[j] = fmaf(w10, v[j], fmaf(w11, v[j + 1], fmaf(w12, v[j + 2], acc1[j])));
            }
        }
    }
    size_t o = (size_t)b * 2 * HW + (size_t)y * WW + x0;
    *(float4*)(unary + o)      = make_float4(acc0[0], acc0[1], acc0[2], acc0[3]);
    *(float4*)(unary + o + HW) = make_float4(acc1[0], acc1[1], acc1[2], acc1[3]);
}

// ---------------------------------------------------------------------------
// Kernel 2: one full CRF iteration, fused:
//   softmax(cur) -> vertical 11-tap blur (direct from global, softmax
//   recomputed per tap) -> LDS row buffer -> horizontal 11-tap blur ->
//   + unary -> nxt.
// One block = one image row. 128 threads x 4 px = 512 px.
// LDS layout: index 8+x for x in [0,512); zeros at [3,8) and [520,525)
// implement the horizontal zero-pad; all float4 accesses 16B-aligned.
// ---------------------------------------------------------------------------
__device__ __forceinline__ void sm2(float a, float bch, float k,
                                    float& q0acc, float& q1acc) {
    float d   = fminf(fmaxf(bch - a, -30.f), 30.f);
    float e   = __expf(d);
    float inv = __builtin_amdgcn_rcpf(1.f + e);
    q0acc = fmaf(k, inv, q0acc);
    q1acc = fmaf(k, e * inv, q1acc);
}

__global__ __launch_bounds__(128) void crf_iter(
    const float* __restrict__ cur, const float* __restrict__ unary,
    float* __restrict__ nxt)
{
    __shared__ float v0[528];
    __shared__ float v1[528];

    // XCD-chunked swizzle (grid 8192, %8==0 -> bijective); vertically
    // adjacent rows (the 11-tap reuse window) land on the same XCD L2.
    int bid = blockIdx.x;
    int row = (bid & 7) * 1024 + (bid >> 3);
    int b   = row >> 9;
    int y   = row & 511;
    int tid = threadIdx.x;
    int x0  = tid << 2;

    if (tid < 5) {
        v0[3 + tid] = 0.f; v1[3 + tid] = 0.f;
        v0[520 + tid] = 0.f; v1[520 + tid] = 0.f;
    }

    const float* base0 = cur + (size_t)b * 2 * HW + x0;
    const float* base1 = base0 + HW;

    float a0[4] = {0.f, 0.f, 0.f, 0.f};
    float a1[4] = {0.f, 0.f, 0.f, 0.f};
#pragma unroll
    for (int dy = -5; dy <= 5; ++dy) {
        int yy = y + dy;                 // uniform across block
        if (yy < 0 || yy >= HH) continue;
        float4 c0 = *(const float4*)(base0 + yy * WW);
        float4 c1 = *(const float4*)(base1 + yy * WW);
        float k = GK[dy + 5];
        sm2(c0.x, c1.x, k, a0[0], a1[0]);
        sm2(c0.y, c1.y, k, a0[1], a1[1]);
        sm2(c0.z, c1.z, k, a0[2], a1[2]);
        sm2(c0.w, c1.w, k, a0[3], a1[3]);
    }
    *(float4*)(&v0[8 + x0]) = make_float4(a0[0], a0[1], a0[2], a0[3]);
    *(float4*)(&v1[8 + x0]) = make_float4(a1[0], a1[1], a1[2], a1[3]);
    __syncthreads();

    // hblur: window for px j (j=0..3) is w[j .. j+10], w[t] = v[8+x0-5+t].
    // Load 5 aligned float4s per channel covering indices [x0, x0+20).
    float4 A0 = *(const float4*)(&v0[x0]);
    float4 B0 = *(const float4*)(&v0[x0 + 4]);
    float4 C0 = *(const float4*)(&v0[x0 + 8]);
    float4 D0 = *(const float4*)(&v0[x0 + 12]);
    float4 E0 = *(const float4*)(&v0[x0 + 16]);
    float4 A1 = *(const float4*)(&v1[x0]);
    float4 B1 = *(const float4*)(&v1[x0 + 4]);
    float4 C1 = *(const float4*)(&v1[x0 + 8]);
    float4 D1 = *(const float4*)(&v1[x0 + 12]);
    float4 E1 = *(const float4*)(&v1[x0 + 16]);
    float w0[14] = {A0.w, B0.x, B0.y, B0.z, B0.w, C0.x, C0.y, C0.z, C0.w,
                    D0.x, D0.y, D0.z, D0.w, E0.x};
    float w1[14] = {A1.w, B1.x, B1.y, B1.z, B1.w, C1.x, C1.y, C1.z, C1.w,
                    D1.x, D1.y, D1.z, D1.w, E1.x};

    size_t o = (size_t)b * 2 * HW + (size_t)y * WW + x0;
    float4 u0 = *(const float4*)(unary + o);
    float4 u1 = *(const float4*)(unary + o + HW);

    float r0[4], r1[4];
#pragma unroll
    for (int j = 0; j < 4; ++j) {
        float s0 = 0.f, s1 = 0.f;
#pragma unroll
        for (int t = 0; t < 11; ++t) {
            s0 = fmaf(GK[t], w0[j + t], s0);
            s1 = fmaf(GK[t], w1[j + t], s1);
        }
        r0[j] = s0; r1[j] = s1;
    }
    *(float4*)(nxt + o)      = make_float4(u0.x + r0[0], u0.y + r0[1],
                                           u0.z + r0[2], u0.w + r0[3]);
    *(float4*)(nxt + o + HW) = make_float4(u1.x + r1[0], u1.y + r1[1],
                                           u1.z + r1[2], u1.w + r1[3]);
}

extern "C" void kernel_launch(void* const* d_in, const int* in_sizes, int n_in,
                              void* d_out, int out_size, void* d_ws, size_t ws_size,
                              hipStream_t stream) {
    const float* x    = (const float*)d_in[0];   // (16,3,512,512)
    const float* w    = (const float*)d_in[1];   // (2,3,3,3)
    const float* bias = (const float*)d_in[2];   // (2,)

    float* out   = (float*)d_out;                    // (16,2,512,512)
    float* unary = (float*)d_ws;                     // 33.5 MB
    float* tmp   = unary + (size_t)BB * 2 * HW;      // 33.5 MB

    conv3x3_v4<<<4096, 256, 0, stream>>>(x, w, bias, unary);
    // iter 0 reads unary as cur (cur == logits == unary initially)
    crf_iter<<<8192, 128, 0, stream>>>(unary, unary, out);   // it0 -> out
    crf_iter<<<8192, 128, 0, stream>>>(out,   unary, tmp);   // it1 -> tmp
    crf_iter<<<8192, 128, 0, stream>>>(tmp,   unary, out);   // it2 -> out
    crf_iter<<<8192, 128, 0, stream>>>(out,   unary, tmp);   // it3 -> tmp
    crf_iter<<<8192, 128, 0, stream>>>(tmp,   unary, out);   // it4 -> out
}

// Round 3
// 122.937 us; speedup vs baseline: 3.5824x; 1.1739x over previous
//
#include <hip/hip_runtime.h>

constexpr int BB = 16;        // batch
constexpr int HH = 512;
constexpr int WW = 512;
constexpr int HW = HH * WW;   // 262144 = 2^18

// 11-tap Gaussian, theta=1, normalized (== normal pdf values to ~1e-8 rel).
__device__ constexpr float GK[11] = {
    1.4867195147342977e-06f,
    1.3383022576488537e-04f,
    4.4318484119380075e-03f,
    5.3990966513188063e-02f,
    2.4197072451914337e-01f,
    3.9894228040143270e-01f,
    2.4197072451914337e-01f,
    5.3990966513188063e-02f,
    4.4318484119380075e-03f,
    1.3383022576488537e-04f,
    1.4867195147342977e-06f,
};

// ---------------------------------------------------------------------------
// Kernel 1: 3x3 conv, C_in=3 -> C_out=2, SAME zero-pad.
// 2 output rows x 8 px per thread. All 54 weights hoisted via float4 loads.
// Input rows y0-1..y0+2 shared between both output rows.
// ---------------------------------------------------------------------------
__global__ __launch_bounds__(256) void conv3x3_v8(
    const float* __restrict__ x, const float* __restrict__ w,
    const float* __restrict__ bias, float* __restrict__ unary)
{
    // XCD-chunked swizzle (grid 1024, %8==0 -> bijective)
    int bid = blockIdx.x;
    int sb  = (bid & 7) * 128 + (bid >> 3);
    int t   = sb * 256 + threadIdx.x;        // 262,144 threads
    int b   = t >> 14;                       // 16384 threads / image
    int rem = t & 16383;
    int y0  = (rem >> 6) << 1;               // row pair start: 0,2,..,510
    int xs  = (rem & 63) << 3;               // 8-px strip start

    // hoist weights: w is 54 contiguous floats (2,3,3,3)
    float W[56];
#pragma unroll
    for (int i = 0; i < 13; ++i)
        *(float4*)&W[4 * i] = *(const float4*)(w + 4 * i);
    W[52] = w[52];
    W[53] = w[53];
    float b0 = bias[0], b1 = bias[1];

    float acc0[2][8], acc1[2][8];
#pragma unroll
    for (int r = 0; r < 2; ++r)
#pragma unroll
        for (int j = 0; j < 8; ++j) { acc0[r][j] = b0; acc1[r][j] = b1; }

    const float* xb = x + (size_t)b * 3 * HW;
#pragma unroll
    for (int ci = 0; ci < 3; ++ci) {
        const float* xc = xb + ci * HW;
#pragma unroll
        for (int iy = 0; iy < 4; ++iy) {     // input rows y0-1 .. y0+2
            int yy = y0 - 1 + iy;
            if (yy < 0 || yy >= HH) continue;   // uniform branch
            const float* r = xc + yy * WW;
            float4 cA = *(const float4*)(r + xs);
            float4 cB = *(const float4*)(r + xs + 4);
            float l  = (xs > 0)       ? r[xs - 1] : 0.f;
            float rr = (xs < WW - 8)  ? r[xs + 8] : 0.f;
            float v[10] = {l, cA.x, cA.y, cA.z, cA.w,
                           cB.x, cB.y, cB.z, cB.w, rr};
#pragma unroll
            for (int orow = 0; orow < 2; ++orow) {
                int kh = iy - orow;
                if (kh < 0 || kh > 2) continue;  // compile-time
                float w00 = W[ci * 9 + kh * 3 + 0];
                float w01 = W[ci * 9 + kh * 3 + 1];
                float w02 = W[ci * 9 + kh * 3 + 2];
                float w10 = W[27 + ci * 9 + kh * 3 + 0];
                float w11 = W[27 + ci * 9 + kh * 3 + 1];
                float w12 = W[27 + ci * 9 + kh * 3 + 2];
#pragma unroll
                for (int j = 0; j < 8; ++j) {
                    acc0[orow][j] = fmaf(w00, v[j],
                                    fmaf(w01, v[j + 1],
                                    fmaf(w02, v[j + 2], acc0[orow][j])));
                    acc1[orow][j] = fmaf(w10, v[j],
                                    fmaf(w11, v[j + 1],
                                    fmaf(w12, v[j + 2], acc1[orow][j])));
                }
            }
        }
    }
#pragma unroll
    for (int orow = 0; orow < 2; ++orow) {
        size_t o = (size_t)b * 2 * HW + (size_t)(y0 + orow) * WW + xs;
        *(float4*)(unary + o)          = make_float4(acc0[orow][0], acc0[orow][1], acc0[orow][2], acc0[orow][3]);
        *(float4*)(unary + o + 4)      = make_float4(acc0[orow][4], acc0[orow][5], acc0[orow][6], acc0[orow][7]);
        *(float4*)(unary + o + HW)     = make_float4(acc1[orow][0], acc1[orow][1], acc1[orow][2], acc1[orow][3]);
        *(float4*)(unary + o + HW + 4) = make_float4(acc1[orow][4], acc1[orow][5], acc1[orow][6], acc1[orow][7]);
    }
}

// ---------------------------------------------------------------------------
// Kernel 2: one CRF iteration, 4 output rows per block.
// Softmax computed ONCE per input row (14 rows per 4 output rows vs 11/row),
// accumulated into 4 vertical-blur row accumulators with compile-time taps.
// Then per-row LDS exchange for the horizontal blur + unary add.
// ---------------------------------------------------------------------------
__device__ __forceinline__ void sm2(float a, float bch,
                                    float& q0, float& q1) {
    float d   = fminf(fmaxf(bch - a, -30.f), 30.f);
    float e   = __expf(d);
    float inv = __builtin_amdgcn_rcpf(1.f + e);
    q0 = inv;
    q1 = e * inv;
}

__global__ __launch_bounds__(128) void crf_iter4(
    const float* __restrict__ cur, const float* __restrict__ unary,
    float* __restrict__ nxt)
{
    __shared__ float v0[4][528];
    __shared__ float v1[4][528];

    // grid 2048 (%8==0): XCD-chunked swizzle; vertically adjacent tiles
    // (sharing the +-5 row halo) land on the same XCD L2.
    int bid  = blockIdx.x;
    int tile = (bid & 7) * 256 + (bid >> 3);
    int b    = tile >> 7;                 // 128 tiles / image
    int y0   = (tile & 127) << 2;         // first of 4 output rows
    int tid  = threadIdx.x;
    int x0   = tid << 2;

    if (tid < 5) {
#pragma unroll
        for (int r = 0; r < 4; ++r) {
            v0[r][3 + tid] = 0.f;   v1[r][3 + tid] = 0.f;
            v0[r][520 + tid] = 0.f; v1[r][520 + tid] = 0.f;
        }
    }

    const float* base0 = cur + (size_t)b * 2 * HW + x0;
    const float* base1 = base0 + HW;

    float acc0[4][4] = {{0.f}};
    float acc1[4][4] = {{0.f}};
#pragma unroll
    for (int i = 0; i < 14; ++i) {        // input rows y0-5 .. y0+8
        int yy = y0 + i - 5;
        if (yy < 0 || yy >= HH) continue; // uniform branch
        float4 c0 = *(const float4*)(base0 + yy * WW);
        float4 c1 = *(const float4*)(base1 + yy * WW);
        float q0[4], q1[4];
        sm2(c0.x, c1.x, q0[0], q1[0]);
        sm2(c0.y, c1.y, q0[1], q1[1]);
        sm2(c0.z, c1.z, q0[2], q1[2]);
        sm2(c0.w, c1.w, q0[3], q1[3]);
        // output row y0+r gets tap GK[i-r] (valid when 0 <= i-r <= 10)
#pragma unroll
        for (int r = 0; r < 4; ++r) {
            int d = i - r;
            if (d < 0 || d > 10) continue;    // compile-time
            float k = GK[d];
#pragma unroll
            for (int j = 0; j < 4; ++j) {
                acc0[r][j] = fmaf(k, q0[j], acc0[r][j]);
                acc1[r][j] = fmaf(k, q1[j], acc1[r][j]);
            }
        }
    }
#pragma unroll
    for (int r = 0; r < 4; ++r) {
        *(float4*)(&v0[r][8 + x0]) = make_float4(acc0[r][0], acc0[r][1], acc0[r][2], acc0[r][3]);
        *(float4*)(&v1[r][8 + x0]) = make_float4(acc1[r][0], acc1[r][1], acc1[r][2], acc1[r][3]);
    }
    __syncthreads();

#pragma unroll
    for (int r = 0; r < 4; ++r) {
        float4 A0 = *(const float4*)(&v0[r][x0]);
        float4 B0 = *(const float4*)(&v0[r][x0 + 4]);
        float4 C0 = *(const float4*)(&v0[r][x0 + 8]);
        float4 D0 = *(const float4*)(&v0[r][x0 + 12]);
        float4 E0 = *(const float4*)(&v0[r][x0 + 16]);
        float4 A1 = *(const float4*)(&v1[r][x0]);
        float4 B1 = *(const float4*)(&v1[r][x0 + 4]);
        float4 C1 = *(const float4*)(&v1[r][x0 + 8]);
        float4 D1 = *(const float4*)(&v1[r][x0 + 12]);
        float4 E1 = *(const float4*)(&v1[r][x0 + 16]);
        float w0[14] = {A0.w, B0.x, B0.y, B0.z, B0.w, C0.x, C0.y, C0.z, C0.w,
                        D0.x, D0.y, D0.z, D0.w, E0.x};
        float w1[14] = {A1.w, B1.x, B1.y, B1.z, B1.w, C1.x, C1.y, C1.z, C1.w,
                        D1.x, D1.y, D1.z, D1.w, E1.x};

        size_t o = (size_t)b * 2 * HW + (size_t)(y0 + r) * WW + x0;
        float4 u0 = *(const float4*)(unary + o);
        float4 u1 = *(const float4*)(unary + o + HW);

        float r0[4], r1[4];
#pragma unroll
        for (int j = 0; j < 4; ++j) {
            float s0 = 0.f, s1 = 0.f;
#pragma unroll
            for (int t = 0; t < 11; ++t) {
                s0 = fmaf(GK[t], w0[j + t], s0);
                s1 = fmaf(GK[t], w1[j + t], s1);
            }
            r0[j] = s0; r1[j] = s1;
        }
        *(float4*)(nxt + o)      = make_float4(u0.x + r0[0], u0.y + r0[1],
                                               u0.z + r0[2], u0.w + r0[3]);
        *(float4*)(nxt + o + HW) = make_float4(u1.x + r1[0], u1.y + r1[1],
                                               u1.z + r1[2], u1.w + r1[3]);
    }
}

extern "C" void kernel_launch(void* const* d_in, const int* in_sizes, int n_in,
                              void* d_out, int out_size, void* d_ws, size_t ws_size,
                              hipStream_t stream) {
    const float* x    = (const float*)d_in[0];   // (16,3,512,512)
    const float* w    = (const float*)d_in[1];   // (2,3,3,3)
    const float* bias = (const float*)d_in[2];   // (2,)

    float* out   = (float*)d_out;                    // (16,2,512,512)
    float* unary = (float*)d_ws;                     // 33.5 MB
    float* tmp   = unary + (size_t)BB * 2 * HW;      // 33.5 MB

    conv3x3_v8<<<1024, 256, 0, stream>>>(x, w, bias, unary);
    // iter 0 reads unary as cur (cur == logits == unary initially)
    crf_iter4<<<2048, 128, 0, stream>>>(unary, unary, out);   // it0 -> out
    crf_iter4<<<2048, 128, 0, stream>>>(out,   unary, tmp);   // it1 -> tmp
    crf_iter4<<<2048, 128, 0, stream>>>(tmp,   unary, out);   // it2 -> out
    crf_iter4<<<2048, 128, 0, stream>>>(out,   unary, tmp);   // it3 -> tmp
    crf_iter4<<<2048, 128, 0, stream>>>(tmp,   unary, out);   // it4 -> out
}

// Round 4
// 93.286 us; speedup vs baseline: 4.7210x; 1.3179x over previous
//
#include <hip/hip_runtime.h>

constexpr int BB = 16;        // batch
constexpr int HH = 512;
constexpr int WW = 512;
constexpr int HW = HH * WW;   // 262144 = 2^18
constexpr int NP1 = BB * HW;  // one single-channel plane: 4,194,304 floats

// 11-tap Gaussian, theta=1, normalized (== normal pdf values to ~1e-8 rel).
__device__ constexpr float GK[11] = {
    1.4867195147342977e-06f,
    1.3383022576488537e-04f,
    4.4318484119380075e-03f,
    5.3990966513188063e-02f,
    2.4197072451914337e-01f,
    3.9894228040143270e-01f,
    2.4197072451914337e-01f,
    5.3990966513188063e-02f,
    4.4318484119380075e-03f,
    1.3383022576488537e-04f,
    1.4867195147342977e-06f,
};
// prefix sums of the smallest taps: PFX[k] = GK[0]+..+GK[k-1]
__device__ constexpr float PFX[6] = {
    0.0f,
    1.4867195147342977e-06f,
    1.3531694527962e-04f,
    4.5671653572176e-03f,
    5.8558131870406e-02f,
    3.0052885638955e-01f,
};

// blur(ones) separable factor with zero padding: missing taps at each edge
__device__ __forceinline__ float edgeS(int i) {
    float s = 1.f;
    if (i < 5)   s -= PFX[5 - i];
    if (i > 506) s -= PFX[i - 506];
    return s;
}

__device__ __forceinline__ float sig1(float d) {
    // q1 = e^d / (1 + e^d), clamped for overflow safety
    d = fminf(fmaxf(d, -30.f), 30.f);
    float e = __expf(d);
    return e * __builtin_amdgcn_rcpf(1.f + e);
}

// ---------------------------------------------------------------------------
// Kernel 1: 3x3 conv, C_in=3 -> C_out=2, SAME zero-pad.
// 2 output rows x 8 px per thread; weights hoisted.
// Writes u0 plane and du = u1 - u0 plane (single channel each).
// ---------------------------------------------------------------------------
__global__ __launch_bounds__(256) void conv3x3_du(
    const float* __restrict__ x, const float* __restrict__ w,
    const float* __restrict__ bias, float* __restrict__ u0p,
    float* __restrict__ dup)
{
    int bid = blockIdx.x;
    int sb  = (bid & 7) * 128 + (bid >> 3);     // grid 1024, bijective
    int t   = sb * 256 + threadIdx.x;
    int b   = t >> 14;
    int rem = t & 16383;
    int y0  = (rem >> 6) << 1;
    int xs  = (rem & 63) << 3;

    float W[56];
#pragma unroll
    for (int i = 0; i < 13; ++i)
        *(float4*)&W[4 * i] = *(const float4*)(w + 4 * i);
    W[52] = w[52];
    W[53] = w[53];
    float b0 = bias[0], b1 = bias[1];

    float acc0[2][8], acc1[2][8];
#pragma unroll
    for (int r = 0; r < 2; ++r)
#pragma unroll
        for (int j = 0; j < 8; ++j) { acc0[r][j] = b0; acc1[r][j] = b1; }

    const float* xb = x + (size_t)b * 3 * HW;
#pragma unroll
    for (int ci = 0; ci < 3; ++ci) {
        const float* xc = xb + ci * HW;
#pragma unroll
        for (int iy = 0; iy < 4; ++iy) {
            int yy = y0 - 1 + iy;
            if (yy < 0 || yy >= HH) continue;   // uniform
            const float* r = xc + yy * WW;
            float4 cA = *(const float4*)(r + xs);
            float4 cB = *(const float4*)(r + xs + 4);
            float l  = (xs > 0)      ? r[xs - 1] : 0.f;
            float rr = (xs < WW - 8) ? r[xs + 8] : 0.f;
            float v[10] = {l, cA.x, cA.y, cA.z, cA.w,
                           cB.x, cB.y, cB.z, cB.w, rr};
#pragma unroll
            for (int orow = 0; orow < 2; ++orow) {
                int kh = iy - orow;
                if (kh < 0 || kh > 2) continue;  // compile-time
                float w00 = W[ci * 9 + kh * 3 + 0];
                float w01 = W[ci * 9 + kh * 3 + 1];
                float w02 = W[ci * 9 + kh * 3 + 2];
                float w10 = W[27 + ci * 9 + kh * 3 + 0];
                float w11 = W[27 + ci * 9 + kh * 3 + 1];
                float w12 = W[27 + ci * 9 + kh * 3 + 2];
#pragma unroll
                for (int j = 0; j < 8; ++j) {
                    acc0[orow][j] = fmaf(w00, v[j],
                                    fmaf(w01, v[j + 1],
                                    fmaf(w02, v[j + 2], acc0[orow][j])));
                    acc1[orow][j] = fmaf(w10, v[j],
                                    fmaf(w11, v[j + 1],
                                    fmaf(w12, v[j + 2], acc1[orow][j])));
                }
            }
        }
    }
#pragma unroll
    for (int orow = 0; orow < 2; ++orow) {
        size_t o = (size_t)b * HW + (size_t)(y0 + orow) * WW + xs;
        *(float4*)(u0p + o)     = make_float4(acc0[orow][0], acc0[orow][1], acc0[orow][2], acc0[orow][3]);
        *(float4*)(u0p + o + 4) = make_float4(acc0[orow][4], acc0[orow][5], acc0[orow][6], acc0[orow][7]);
        *(float4*)(dup + o)     = make_float4(acc1[orow][0] - acc0[orow][0], acc1[orow][1] - acc0[orow][1],
                                              acc1[orow][2] - acc0[orow][2], acc1[orow][3] - acc0[orow][3]);
        *(float4*)(dup + o + 4) = make_float4(acc1[orow][4] - acc0[orow][4], acc1[orow][5] - acc0[orow][5],
                                              acc1[orow][6] - acc0[orow][6], acc1[orow][7] - acc0[orow][7]);
    }
}

// ---------------------------------------------------------------------------
// Kernel 2: one CRF iteration on the channel-difference state.
//   m1 = blur(sigmoid(d));  d' = du + 2*m1 - Sx*Sy
// MODE 0: dcur == du (first iteration), write d' plane
// MODE 1: middle iteration, write d' plane
// MODE 2: final: out0 = u0 + SxSy - m1 ; out1 = u0 + du + m1  (NCHW out)
// 8 output rows per block, 128 threads x 4 px, full 512-wide rows.
// ---------------------------------------------------------------------------
template <int MODE>
__global__ __launch_bounds__(128) void crf_diff(
    const float* __restrict__ dcur, const float* __restrict__ dup,
    const float* __restrict__ u0p, float* __restrict__ outp)
{
    __shared__ float v[8][528];

    int bid  = blockIdx.x;
    int tile = (bid & 7) * 128 + (bid >> 3);   // grid 1024, bijective
    int b    = tile >> 6;                      // 64 tiles / image
    int y0   = (tile & 63) << 3;               // 8 output rows
    int tid  = threadIdx.x;
    int x0   = tid << 2;

    if (tid < 5) {
#pragma unroll
        for (int r = 0; r < 8; ++r) {
            v[r][3 + tid] = 0.f;
            v[r][520 + tid] = 0.f;
        }
    }

    const float* dbase = dcur + (size_t)b * HW + x0;

    float acc[8][4] = {{0.f}};
#pragma unroll
    for (int i = 0; i < 18; ++i) {             // input rows y0-5 .. y0+12
        int yy = y0 + i - 5;
        if (yy < 0 || yy >= HH) continue;      // uniform
        float4 dv = *(const float4*)(dbase + yy * WW);
        float q[4] = {sig1(dv.x), sig1(dv.y), sig1(dv.z), sig1(dv.w)};
#pragma unroll
        for (int r = 0; r < 8; ++r) {
            int dt = i - r;
            if (dt < 0 || dt > 10) continue;   // compile-time
            float k = GK[dt];
#pragma unroll
            for (int j = 0; j < 4; ++j)
                acc[r][j] = fmaf(k, q[j], acc[r][j]);
        }
    }
#pragma unroll
    for (int r = 0; r < 8; ++r)
        *(float4*)(&v[r][8 + x0]) = make_float4(acc[r][0], acc[r][1], acc[r][2], acc[r][3]);
    __syncthreads();

    float Sx[4];
#pragma unroll
    for (int j = 0; j < 4; ++j) Sx[j] = edgeS(x0 + j);

#pragma unroll
    for (int r = 0; r < 8; ++r) {
        int yy = y0 + r;
        float Sy = edgeS(yy);

        float4 A = *(const float4*)(&v[r][x0]);
        float4 Bq = *(const float4*)(&v[r][x0 + 4]);
        float4 C = *(const float4*)(&v[r][x0 + 8]);
        float4 D = *(const float4*)(&v[r][x0 + 12]);
        float4 E = *(const float4*)(&v[r][x0 + 16]);
        float wv[14] = {A.w, Bq.x, Bq.y, Bq.z, Bq.w, C.x, C.y, C.z, C.w,
                        D.x, D.y, D.z, D.w, E.x};

        float m1[4];
#pragma unroll
        for (int j = 0; j < 4; ++j) {
            float s = 0.f;
#pragma unroll
            for (int t = 0; t < 11; ++t)
                s = fmaf(GK[t], wv[j + t], s);
            m1[j] = s;
        }

        size_t po = (size_t)b * HW + (size_t)yy * WW + x0;
        float4 duv = *(const float4*)(dup + po);

        if (MODE == 2) {
            float4 u0v = *(const float4*)(u0p + po);
            size_t oo = (size_t)b * 2 * HW + (size_t)yy * WW + x0;
            float o0[4], o1[4];
#pragma unroll
            for (int j = 0; j < 4; ++j) {
                float S = Sx[j] * Sy;
                float u0s = (&u0v.x)[j];
                float dus = (&duv.x)[j];
                o0[j] = u0s + (S - m1[j]);
                o1[j] = (u0s + dus) + m1[j];
            }
            *(float4*)(outp + oo)      = make_float4(o0[0], o0[1], o0[2], o0[3]);
            *(float4*)(outp + oo + HW) = make_float4(o1[0], o1[1], o1[2], o1[3]);
        } else {
            float dn[4];
#pragma unroll
            for (int j = 0; j < 4; ++j) {
                float S = Sx[j] * Sy;
                dn[j] = (&duv.x)[j] + fmaf(2.f, m1[j], -S);
            }
            *(float4*)(outp + po) = make_float4(dn[0], dn[1], dn[2], dn[3]);
        }
    }
}

extern "C" void kernel_launch(void* const* d_in, const int* in_sizes, int n_in,
                              void* d_out, int out_size, void* d_ws, size_t ws_size,
                              hipStream_t stream) {
    const float* x    = (const float*)d_in[0];   // (16,3,512,512)
    const float* w    = (const float*)d_in[1];   // (2,3,3,3)
    const float* bias = (const float*)d_in[2];   // (2,)

    float* out = (float*)d_out;                  // (16,2,512,512)
    float* u0p = (float*)d_ws;                   // 16.8 MB
    float* dup = u0p + NP1;                      // 16.8 MB
    float* dA  = dup + NP1;                      // 16.8 MB
    float* dB  = dA + NP1;                       // 16.8 MB

    conv3x3_du<<<1024, 256, 0, stream>>>(x, w, bias, u0p, dup);
    crf_diff<0><<<1024, 128, 0, stream>>>(dup, dup, u0p, dA);   // it0
    crf_diff<1><<<1024, 128, 0, stream>>>(dA,  dup, u0p, dB);   // it1
    crf_diff<1><<<1024, 128, 0, stream>>>(dB,  dup, u0p, dA);   // it2
    crf_diff<1><<<1024, 128, 0, stream>>>(dA,  dup, u0p, dB);   // it3
    crf_diff<2><<<1024, 128, 0, stream>>>(dB,  dup, u0p, out);  // it4 -> out
}